// Round 8
// baseline (61.036 us; speedup 1.0000x reference)
//
#include <hip/hip_runtime.h>

// Chamfer distance via MFMA, B=4, N=M=8192, fp32 3D points.
// d[n,m] = qsq[n] + tsq[m] - 2*q[n].t[m] via v_mfma_f32_16x16x32_bf16 with
// split-precision bf16 operands (13 of 32 k-slots used, rest zero):
//   s0..s8 : per coord c: qh_c*(-2th_c), qh_c*(-2tl_c), ql_c*(-2th_c)
//   s9,s10 : qsq_h*1, qsq_l*1   s11,s12: 1*tsq_h, 1*tsq_l   s13..31: 0
// Round-8: 16x16 shape -> f32x4 accumulators (4 VGPR/result, not 16).
// R4-R7's stall was an AGPR flood: f32x16 accumulators spilled to AGPRs
// (VGPR_Count=36 tell) costing ~5 VALU ops/element in accvgpr moves.
// Small accumulators + no occupancy-forcing launch bounds keep everything
// in arch VGPRs. QT=2 query tiles/wave, 2 B-tiles/iter (v_min3 pairing),
// B-segment (32KB) staged in LDS shared by 8 waves.

typedef short bf16x8 __attribute__((ext_vector_type(8)));
typedef float f32x4  __attribute__((ext_vector_type(4)));

constexpr int Bc  = 4;
constexpr int Nc  = 8192;
constexpr int NT  = Nc / 16;    // 512 tiles of 16 points
constexpr int SEG = 16;         // target segments
constexpr int TPS = NT / SEG;   // 32 target tiles per segment
constexpr int QT  = 2;          // query tiles per wave

__device__ inline unsigned short f2bf(float x) {
    unsigned u = __float_as_uint(x);
    unsigned r = (u + 0x7FFFu + ((u >> 16) & 1u)) >> 16;   // RNE
    return (unsigned short)r;
}
__device__ inline float bf2f(unsigned short h) {
    return __uint_as_float(((unsigned)h) << 16);
}
__device__ inline unsigned pack2(unsigned short lo, unsigned short hi) {
    return (unsigned)lo | ((unsigned)hi << 16);
}

__global__ void init_out_inf(float* __restrict__ out, int n) {
    int i = blockIdx.x * blockDim.x + threadIdx.x;
    int stride = gridDim.x * blockDim.x;
    for (; i < n; i += stride) out[i] = __uint_as_float(0x7F800000u);
}

// Pack BOTH clouds into q-form and t-form 16x16x32 fragment arrays.
// qf/tf: [2 clouds][Bc*NT*64] uint4. blockIdx.y = cloud.
// Lane l of tile: point = tile*16 + (l&15), k-group kg = l>>4 (8 k-slots each).
// kg0 -> s0..7, kg1 -> s8..15 (s13..15 zero), kg2/kg3 -> all zero.
__global__ void pack_both(const float* __restrict__ xyz1,
                          const float* __restrict__ xyz2,
                          uint4* __restrict__ qf, uint4* __restrict__ tf) {
    const int tid   = blockIdx.x * 256 + threadIdx.x;   // [0, Bc*NT*64)
    const int cloud = blockIdx.y;
    const float* src = cloud ? xyz2 : xyz1;
    const int lane = tid & 63;
    const int gt   = tid >> 6;           // global tile 0..Bc*NT-1
    const int b    = gt >> 9;            // NT = 512
    const int tile = gt & (NT - 1);
    const int pt   = tile * 16 + (lane & 15);
    const int kg   = lane >> 4;
    const size_t FR = (size_t)Bc * NT * 64;

    uint4 q = {0, 0, 0, 0}, t = {0, 0, 0, 0};
    if (kg < 2) {
        const float* p = src + ((size_t)b * Nc + pt) * 3;
        float x = p[0], y = p[1], z = p[2];
        float sq = x * x + y * y + z * z;
        unsigned short xh = f2bf(x), yh = f2bf(y), zh = f2bf(z);
        unsigned short xl = f2bf(x - bf2f(xh)), yl = f2bf(y - bf2f(yh)), zl = f2bf(z - bf2f(zh));
        unsigned short sh = f2bf(sq), sl = f2bf(sq - bf2f(sh));
        unsigned short m2xh = f2bf(-2.0f * bf2f(xh));
        unsigned short m2yh = f2bf(-2.0f * bf2f(yh));
        unsigned short m2zh = f2bf(-2.0f * bf2f(zh));
        unsigned short m2xl = f2bf(-2.0f * (x - bf2f(xh)));
        unsigned short m2yl = f2bf(-2.0f * (y - bf2f(yh)));
        unsigned short m2zl = f2bf(-2.0f * (z - bf2f(zh)));
        const unsigned short ONE = 0x3F80;
        if (kg == 0) {
            // s0..s7
            q.x = pack2(xh, xh); q.y = pack2(xl, yh);
            q.z = pack2(yh, yl); q.w = pack2(zh, zh);
            t.x = pack2(m2xh, m2xl); t.y = pack2(m2xh, m2yh);
            t.z = pack2(m2yl, m2yh); t.w = pack2(m2zh, m2zl);
        } else {
            // s8..s15 (s13..15 zero)
            q.x = pack2(zl, sh); q.y = pack2(sl, ONE);
            q.z = pack2(ONE, 0); q.w = 0;
            t.x = pack2(m2zh, ONE); t.y = pack2(ONE, sh);
            t.z = pack2(sl, 0);     t.w = 0;
        }
    }
    qf[(size_t)cloud * FR + tid] = q;
    tf[(size_t)cloud * FR + tid] = t;
}

// Main: grid (NT/(8*QT), SEG, 2*Bc), 512 threads = 8 waves.
// blockIdx.z: dir = z>>2 (0: xyz1->xyz2, 1: xyz2->xyz1), b = z&3.
// Block stages its 32KB B-segment in LDS; wave w sweeps it against query
// tiles tile0+{0,1} with running row-min in f32x4 registers.
__global__ __launch_bounds__(512) void chamfer_16(
    const uint4* __restrict__ qf,   // [2][Bc*NT*64]
    const uint4* __restrict__ tf,   // [2][Bc*NT*64]
    float* __restrict__ out) {
    __shared__ uint4 sB[TPS * 64];                 // 32 KB
    const int tid = threadIdx.x, lane = tid & 63, wave = tid >> 6;
    const int z = blockIdx.z, dir = z >> 2, b = z & 3, seg = blockIdx.y;
    const int qc = dir, tc = dir ^ 1;
    const size_t FR = (size_t)Bc * NT * 64;

    // Stage B-segment: 2048 uint4, 512 threads -> 4 coalesced 16B stores each.
    const uint4* bseg = tf + (size_t)tc * FR + ((size_t)(b * NT + seg * TPS)) * 64;
    #pragma unroll
    for (int i = 0; i < TPS * 64 / 512; ++i)
        sB[tid + i * 512] = bseg[tid + i * 512];

    const int tile0 = blockIdx.x * (8 * QT) + wave * QT;
    bf16x8 av[QT];
    #pragma unroll
    for (int qt = 0; qt < QT; ++qt)
        av[qt] = __builtin_bit_cast(bf16x8,
            qf[(size_t)qc * FR + ((size_t)(b * NT + tile0 + qt)) * 64 + lane]);

    f32x4 zc{};
    float rmin[QT][4];
    #pragma unroll
    for (int qt = 0; qt < QT; ++qt)
        #pragma unroll
        for (int r = 0; r < 4; ++r) rmin[qt][r] = INFINITY;

    __syncthreads();

    // Sweep 32 B-tiles from LDS, 2 per iteration; min3 pairs the two results.
    #pragma unroll 4
    for (int mt = 0; mt < TPS; mt += 2) {
        const bf16x8 bv0 = __builtin_bit_cast(bf16x8, sB[mt * 64 + lane]);
        const bf16x8 bv1 = __builtin_bit_cast(bf16x8, sB[mt * 64 + 64 + lane]);
        #pragma unroll
        for (int qt = 0; qt < QT; ++qt) {
            const f32x4 d0 = __builtin_amdgcn_mfma_f32_16x16x32_bf16(av[qt], bv0, zc, 0, 0, 0);
            const f32x4 d1 = __builtin_amdgcn_mfma_f32_16x16x32_bf16(av[qt], bv1, zc, 0, 0, 0);
            #pragma unroll
            for (int r = 0; r < 4; ++r)
                rmin[qt][r] = fminf(rmin[qt][r], fminf(d0[r], d1[r]));  // v_min3
        }
    }

    // Epilogue: C/D 16x16 layout (m89/m91): col = lane&15, row = (lane>>4)*4+r.
    // Reduce over the 16 cols via shfl_xor on lane bits 0..3; lanes 0,16,32,48
    // then hold rows (lane>>4)*4 + r and write 4 atomicMin each.
    #pragma unroll
    for (int qt = 0; qt < QT; ++qt) {
        #pragma unroll
        for (int m = 1; m <= 8; m <<= 1)
            #pragma unroll
            for (int r = 0; r < 4; ++r)
                rmin[qt][r] = fminf(rmin[qt][r], __shfl_xor(rmin[qt][r], m));
        if ((lane & 15) == 0) {
            unsigned* d1p = (unsigned*)out + (size_t)dir * Bc * Nc + (size_t)b * Nc
                          + (size_t)(tile0 + qt) * 16 + (lane >> 4) * 4;
            #pragma unroll
            for (int r = 0; r < 4; ++r)
                atomicMin(&d1p[r], __float_as_uint(fmaxf(rmin[qt][r], 0.0f)));
        }
    }
}

// ---- Fallback (ws too small): round-2 expansion kernel ----
constexpr int QPT = 2, TPB = 256;
__global__ void pack_pts(const float* __restrict__ src, float4* __restrict__ dst, int npts) {
    int i = blockIdx.x * blockDim.x + threadIdx.x;
    if (i < npts) {
        float x = src[3 * i], y = src[3 * i + 1], z = src[3 * i + 2];
        dst[i] = make_float4(x, y, z, x * x + y * y + z * z);
    }
}
__global__ __launch_bounds__(TPB, 8) void chamfer_fb(
    const float* __restrict__ xyz1, const float* __restrict__ xyz2,
    const float4* __restrict__ p1, const float4* __restrict__ p2,
    float* __restrict__ out) {
    const int z = blockIdx.z, dir = z >> 2, b = z & 3, seg = blockIdx.y;
    const float*  qry  = dir ? xyz2 : xyz1;
    const float4* tgt4 = dir ? p1 : p2;
    float* o = out + (size_t)dir * Bc * Nc + (size_t)b * Nc;
    const int q0 = blockIdx.x * (TPB * QPT) + threadIdx.x;
    float m2x[QPT], m2y[QPT], m2z[QPT], qsq[QPT];
    #pragma unroll
    for (int j = 0; j < QPT; ++j) {
        const float* qp = qry + ((size_t)b * Nc + q0 + j * TPB) * 3;
        float x = qp[0], y = qp[1], zz = qp[2];
        m2x[j] = -2.f * x; m2y[j] = -2.f * y; m2z[j] = -2.f * zz;
        qsq[j] = x * x + y * y + zz * zz;
    }
    constexpr int seg_pts = Nc / 16;
    const float4* t = tgt4 + (size_t)b * Nc + (size_t)seg * seg_pts;
    float mn0[QPT], mn1[QPT];
    #pragma unroll
    for (int j = 0; j < QPT; ++j) { mn0[j] = INFINITY; mn1[j] = INFINITY; }
    #pragma unroll 4
    for (int i = 0; i < seg_pts; i += 2) {
        const float4 t0 = t[i], t1 = t[i + 1];
        #pragma unroll
        for (int j = 0; j < QPT; ++j) {
            mn0[j] = fminf(mn0[j], fmaf(m2x[j], t0.x, fmaf(m2y[j], t0.y, fmaf(m2z[j], t0.z, t0.w))));
            mn1[j] = fminf(mn1[j], fmaf(m2x[j], t1.x, fmaf(m2y[j], t1.y, fmaf(m2z[j], t1.z, t1.w))));
        }
    }
    #pragma unroll
    for (int j = 0; j < QPT; ++j) {
        float d = fmaxf(qsq[j] + fminf(mn0[j], mn1[j]), 0.f);
        atomicMin((unsigned*)(o + q0 + j * TPB), __float_as_uint(d));
    }
}

extern "C" void kernel_launch(void* const* d_in, const int* in_sizes, int n_in,
                              void* d_out, int out_size, void* d_ws, size_t ws_size,
                              hipStream_t stream) {
    const float* xyz1 = (const float*)d_in[0];
    const float* xyz2 = (const float*)d_in[1];
    float* out = (float*)d_out;

    const size_t FR = (size_t)Bc * NT * 64;               // 131072 uint4 per array
    const size_t need = 4 * FR * sizeof(uint4);           // 8 MiB (qf[2] + tf[2])

    init_out_inf<<<dim3(64), dim3(256), 0, stream>>>(out, out_size);

    if (ws_size >= need) {
        uint4* qf = (uint4*)d_ws;          // [2][FR]
        uint4* tf = qf + 2 * FR;           // [2][FR]
        pack_both<<<dim3(FR / 256, 2), dim3(256), 0, stream>>>(xyz1, xyz2, qf, tf);
        dim3 grid(NT / (8 * QT), SEG, 2 * Bc);            // 32 x 16 x 8 = 4096 blocks
        chamfer_16<<<grid, dim3(512), 0, stream>>>(qf, tf, out);
    } else if (ws_size >= 2 * (size_t)Bc * Nc * sizeof(float4)) {
        float4* p1 = (float4*)d_ws;
        float4* p2 = p1 + Bc * Nc;
        pack_pts<<<dim3(Bc * Nc / 256), dim3(256), 0, stream>>>(xyz1, p1, Bc * Nc);
        pack_pts<<<dim3(Bc * Nc / 256), dim3(256), 0, stream>>>(xyz2, p2, Bc * Nc);
        dim3 grid(Nc / (TPB * QPT), 16, 2 * Bc);
        chamfer_fb<<<grid, dim3(TPB), 0, stream>>>(xyz1, xyz2, p1, p2, out);
    }
}

// Round 9
// 56.921 us; speedup vs baseline: 1.0723x; 1.0723x over previous
//
#include <hip/hip_runtime.h>

// Chamfer distance via MFMA, B=4, N=M=8192, fp32 3D points.
// d[n,m] = qsq[n] + tsq[m] - 2*q[n].t[m] via v_mfma_f32_32x32x16_bf16 with
// split-precision bf16 operands (13 of 16 k-slots):
//   s0..s8 : per coord c: qh_c*(-2th_c), qh_c*(-2tl_c), ql_c*(-2th_c)
//   s9,s10 : qsq_h*1, qsq_l*1   s11,s12: 1*tsq_h, 1*tsq_l   s13..15: 0
// Round-9: explicit 2-deep SOFTWARE PIPELINE on the R5 base. Per iteration,
// issue MFMAs for tile-pair t+1 BEFORE consuming tile-pair t's results
// (accvgpr_read + v_min3), hiding MFMA latency inside the wave instead of
// relying on scarce resident waves (R4 evidence: 53% issue-idle at 3.4
// waves/SIMD). B-segment (32 KB) staged in LDS, shared by 4 waves,
// conflict-free stride-1 ds_read_b128. No min-occupancy launch_bounds
// (R7's register squeeze). init fused into pack (one fewer launch).

typedef short bf16x8 __attribute__((ext_vector_type(8)));
typedef float f32x16 __attribute__((ext_vector_type(16)));

constexpr int Bc  = 4;
constexpr int Nc  = 8192;
constexpr int NT  = Nc / 32;    // 256 tiles of 32 points
constexpr int SEG = 8;          // target segments
constexpr int TPS = NT / SEG;   // 32 target tiles per segment

__device__ inline unsigned short f2bf(float x) {
    unsigned u = __float_as_uint(x);
    unsigned r = (u + 0x7FFFu + ((u >> 16) & 1u)) >> 16;   // RNE
    return (unsigned short)r;
}
__device__ inline float bf2f(unsigned short h) {
    return __uint_as_float(((unsigned)h) << 16);
}
__device__ inline unsigned pack2(unsigned short lo, unsigned short hi) {
    return (unsigned)lo | ((unsigned)hi << 16);
}

// Packs BOTH clouds into q-form and t-form fragment arrays AND initializes
// out to +inf (tid range [0,65536) == out_size exactly, done on cloud 0).
// qf/tf: [2 clouds][Bc*NT*64] uint4. blockIdx.y = cloud.
__global__ void pack_both(const float* __restrict__ xyz1,
                          const float* __restrict__ xyz2,
                          uint4* __restrict__ qf, uint4* __restrict__ tf,
                          float* __restrict__ out) {
    const int tid   = blockIdx.x * 256 + threadIdx.x;   // [0, Bc*NT*64) = [0,65536)
    const int cloud = blockIdx.y;
    if (cloud == 0) out[tid] = __uint_as_float(0x7F800000u);  // +inf (out_size==65536)
    const float* src = cloud ? xyz2 : xyz1;
    const int lane = tid & 63;
    const int tile = (tid >> 6) & (NT - 1);
    const int b    = tid >> 14;
    const int pt   = tile * 32 + (lane & 31);
    const int kg   = lane >> 5;
    const float* p = src + ((size_t)b * Nc + pt) * 3;
    float x = p[0], y = p[1], z = p[2];
    float sq = x * x + y * y + z * z;
    unsigned short xh = f2bf(x), yh = f2bf(y), zh = f2bf(z);
    unsigned short xl = f2bf(x - bf2f(xh)), yl = f2bf(y - bf2f(yh)), zl = f2bf(z - bf2f(zh));
    unsigned short sh = f2bf(sq), sl = f2bf(sq - bf2f(sh));
    unsigned short m2xh = f2bf(-2.0f * bf2f(xh));
    unsigned short m2yh = f2bf(-2.0f * bf2f(yh));
    unsigned short m2zh = f2bf(-2.0f * bf2f(zh));
    unsigned short m2xl = f2bf(-2.0f * (x - bf2f(xh)));
    unsigned short m2yl = f2bf(-2.0f * (y - bf2f(yh)));
    unsigned short m2zl = f2bf(-2.0f * (z - bf2f(zh)));
    const unsigned short ONE = 0x3F80;
    uint4 q, t;
    if (kg == 0) {
        q.x = pack2(xh, xh); q.y = pack2(xl, yh);
        q.z = pack2(yh, yl); q.w = pack2(zh, zh);
        t.x = pack2(m2xh, m2xl); t.y = pack2(m2xh, m2yh);
        t.z = pack2(m2yl, m2yh); t.w = pack2(m2zh, m2zl);
    } else {
        q.x = pack2(zl, sh); q.y = pack2(sl, ONE);
        q.z = pack2(ONE, 0); q.w = 0;
        t.x = pack2(m2zh, ONE); t.y = pack2(ONE, sh);
        t.z = pack2(sl, 0);     t.w = 0;
    }
    const size_t FR = (size_t)Bc * NT * 64;
    qf[(size_t)cloud * FR + tid] = q;
    tf[(size_t)cloud * FR + tid] = t;
}

// Main: grid (NT/4, SEG, 2*Bc), 256 threads = 4 waves.
// blockIdx.z: dir = z>>2 (0: xyz1->xyz2, 1: xyz2->xyz1), b = z&3.
// Block stages its 32KB B-segment in LDS; wave w sweeps it against query
// tile blockIdx.x*4 + w with a 2-deep pipelined running row-min.
__global__ __launch_bounds__(256) void chamfer_pipe(
    const uint4* __restrict__ qf,   // [2][Bc*NT*64]
    const uint4* __restrict__ tf,   // [2][Bc*NT*64]
    float* __restrict__ out) {
    __shared__ uint4 sB[TPS * 64];                 // 32 KB
    const int tid = threadIdx.x, lane = tid & 63, wave = tid >> 6;
    const int z = blockIdx.z, dir = z >> 2, b = z & 3, seg = blockIdx.y;
    const int qc = dir, tc = dir ^ 1;
    const size_t FR = (size_t)Bc * NT * 64;

    // Stage B-segment: 2048 uint4, 256 threads -> 8 coalesced 16B copies each.
    const uint4* bseg = tf + (size_t)tc * FR + ((size_t)(b * NT + seg * TPS)) * 64;
    #pragma unroll
    for (int i = 0; i < TPS * 64 / 256; ++i)
        sB[tid + i * 256] = bseg[tid + i * 256];

    const int n_tile = blockIdx.x * 4 + wave;
    const bf16x8 av = __builtin_bit_cast(bf16x8,
        qf[(size_t)qc * FR + ((size_t)(b * NT + n_tile)) * 64 + lane]);
    f32x16 zc{};
    float rmin[16];
    #pragma unroll
    for (int r = 0; r < 16; ++r) rmin[r] = INFINITY;

    __syncthreads();

    // 2-deep pipeline: issue MFMAs for pair t+1, then consume pair t.
    bf16x8 bv0 = __builtin_bit_cast(bf16x8, sB[lane]);
    bf16x8 bv1 = __builtin_bit_cast(bf16x8, sB[64 + lane]);
    f32x16 dA = __builtin_amdgcn_mfma_f32_32x32x16_bf16(av, bv0, zc, 0, 0, 0);
    f32x16 dB = __builtin_amdgcn_mfma_f32_32x32x16_bf16(av, bv1, zc, 0, 0, 0);
    for (int mt = 2; mt < TPS; mt += 2) {
        const bf16x8 nv0 = __builtin_bit_cast(bf16x8, sB[mt * 64 + lane]);
        const bf16x8 nv1 = __builtin_bit_cast(bf16x8, sB[mt * 64 + 64 + lane]);
        const f32x16 dA2 = __builtin_amdgcn_mfma_f32_32x32x16_bf16(av, nv0, zc, 0, 0, 0);
        const f32x16 dB2 = __builtin_amdgcn_mfma_f32_32x32x16_bf16(av, nv1, zc, 0, 0, 0);
        #pragma unroll
        for (int r = 0; r < 16; ++r)
            rmin[r] = fminf(rmin[r], fminf(dA[r], dB[r]));   // v_min3
        dA = dA2; dB = dB2;
    }
    #pragma unroll
    for (int r = 0; r < 16; ++r)
        rmin[r] = fminf(rmin[r], fminf(dA[r], dB[r]));

    // Epilogue: butterfly over the 32 columns (lane bits 0..4), then lanes
    // 0 and 32 write 16 rows each via one global atomicMin per row.
    #pragma unroll
    for (int m = 1; m <= 16; m <<= 1)
        #pragma unroll
        for (int r = 0; r < 16; ++r)
            rmin[r] = fminf(rmin[r], __shfl_xor(rmin[r], m));
    if ((lane & 31) == 0) {
        const int hi = lane >> 5;
        unsigned* d1p = (unsigned*)out + (size_t)dir * Bc * Nc + (size_t)b * Nc
                      + (size_t)n_tile * 32;
        #pragma unroll
        for (int r = 0; r < 16; ++r) {
            const int row = (r & 3) + 8 * (r >> 2) + 4 * hi;   // C/D layout (m74/m101)
            atomicMin(&d1p[row], __float_as_uint(fmaxf(rmin[r], 0.0f)));
        }
    }
}

// ---- Fallback (ws too small): round-2 expansion kernel ----
constexpr int QPT = 2, TPB = 256;
__global__ void init_out_inf(float* __restrict__ out, int n) {
    int i = blockIdx.x * blockDim.x + threadIdx.x;
    int stride = gridDim.x * blockDim.x;
    for (; i < n; i += stride) out[i] = __uint_as_float(0x7F800000u);
}
__global__ void pack_pts(const float* __restrict__ src, float4* __restrict__ dst, int npts) {
    int i = blockIdx.x * blockDim.x + threadIdx.x;
    if (i < npts) {
        float x = src[3 * i], y = src[3 * i + 1], z = src[3 * i + 2];
        dst[i] = make_float4(x, y, z, x * x + y * y + z * z);
    }
}
__global__ __launch_bounds__(TPB, 8) void chamfer_fb(
    const float* __restrict__ xyz1, const float* __restrict__ xyz2,
    const float4* __restrict__ p1, const float4* __restrict__ p2,
    float* __restrict__ out) {
    const int z = blockIdx.z, dir = z >> 2, b = z & 3, seg = blockIdx.y;
    const float*  qry  = dir ? xyz2 : xyz1;
    const float4* tgt4 = dir ? p1 : p2;
    float* o = out + (size_t)dir * Bc * Nc + (size_t)b * Nc;
    const int q0 = blockIdx.x * (TPB * QPT) + threadIdx.x;
    float m2x[QPT], m2y[QPT], m2z[QPT], qsq[QPT];
    #pragma unroll
    for (int j = 0; j < QPT; ++j) {
        const float* qp = qry + ((size_t)b * Nc + q0 + j * TPB) * 3;
        float x = qp[0], y = qp[1], zz = qp[2];
        m2x[j] = -2.f * x; m2y[j] = -2.f * y; m2z[j] = -2.f * zz;
        qsq[j] = x * x + y * y + zz * zz;
    }
    constexpr int seg_pts = Nc / 16;
    const float4* t = tgt4 + (size_t)b * Nc + (size_t)seg * seg_pts;
    float mn0[QPT], mn1[QPT];
    #pragma unroll
    for (int j = 0; j < QPT; ++j) { mn0[j] = INFINITY; mn1[j] = INFINITY; }
    #pragma unroll 4
    for (int i = 0; i < seg_pts; i += 2) {
        const float4 t0 = t[i], t1 = t[i + 1];
        #pragma unroll
        for (int j = 0; j < QPT; ++j) {
            mn0[j] = fminf(mn0[j], fmaf(m2x[j], t0.x, fmaf(m2y[j], t0.y, fmaf(m2z[j], t0.z, t0.w))));
            mn1[j] = fminf(mn1[j], fmaf(m2x[j], t1.x, fmaf(m2y[j], t1.y, fmaf(m2z[j], t1.z, t1.w))));
        }
    }
    #pragma unroll
    for (int j = 0; j < QPT; ++j) {
        float d = fmaxf(qsq[j] + fminf(mn0[j], mn1[j]), 0.f);
        atomicMin((unsigned*)(o + q0 + j * TPB), __float_as_uint(d));
    }
}

extern "C" void kernel_launch(void* const* d_in, const int* in_sizes, int n_in,
                              void* d_out, int out_size, void* d_ws, size_t ws_size,
                              hipStream_t stream) {
    const float* xyz1 = (const float*)d_in[0];
    const float* xyz2 = (const float*)d_in[1];
    float* out = (float*)d_out;

    const size_t FR = (size_t)Bc * NT * 64;               // 65536 uint4 per array
    const size_t need = 4 * FR * sizeof(uint4);           // 4 MiB (qf[2] + tf[2])

    if (ws_size >= need) {
        uint4* qf = (uint4*)d_ws;          // [2][FR]
        uint4* tf = qf + 2 * FR;           // [2][FR]
        pack_both<<<dim3(FR / 256, 2), dim3(256), 0, stream>>>(xyz1, xyz2, qf, tf, out);
        dim3 grid(NT / 4, SEG, 2 * Bc);                   // 64 x 8 x 8 = 4096 blocks
        chamfer_pipe<<<grid, dim3(256), 0, stream>>>(qf, tf, out);
    } else if (ws_size >= 2 * (size_t)Bc * Nc * sizeof(float4)) {
        init_out_inf<<<dim3(64), dim3(256), 0, stream>>>(out, out_size);
        float4* p1 = (float4*)d_ws;
        float4* p2 = p1 + Bc * Nc;
        pack_pts<<<dim3(Bc * Nc / 256), dim3(256), 0, stream>>>(xyz1, p1, Bc * Nc);
        pack_pts<<<dim3(Bc * Nc / 256), dim3(256), 0, stream>>>(xyz2, p2, Bc * Nc);
        dim3 grid(Nc / (TPB * QPT), 16, 2 * Bc);
        chamfer_fb<<<grid, dim3(TPB), 0, stream>>>(xyz1, xyz2, p1, p2, out);
    }
}